// Round 1
// baseline (121.352 us; speedup 1.0000x reference)
//
#include <hip/hip_runtime.h>
#include <hip/hip_bf16.h>

#define N_NODES 2048
#define EMBED 256
#define STATE 128
#define HID 256
#define N_ACT 256
#define TEAMS 8
#define PAIR_F 14
#define BT_TOTAL 512               // B*T
#define M_TOTAL (BT_TOTAL * N_ACT) // 131072

typedef __bf16 bf16_t;
typedef __bf16 bf16x8 __attribute__((ext_vector_type(8)));
typedef float f32x4 __attribute__((ext_vector_type(4)));

// ---------------- precompute kernels ----------------

// column partial sums of node_embeddings: 64 blocks x 32 nodes
__global__ void k_colsum_part(const float* __restrict__ ne, float* __restrict__ gpart) {
    int b = blockIdx.x;
    int t = threadIdx.x;
    float s = 0.f;
    const float* base = ne + (size_t)b * 32 * EMBED + t;
#pragma unroll
    for (int i = 0; i < 32; ++i) s += base[(size_t)i * EMBED];
    gpart[b * EMBED + t] = s;
}

__global__ void k_colsum_final(const float* __restrict__ gpart, float* __restrict__ gmean) {
    int t = threadIdx.x;
    float s = 0.f;
#pragma unroll 8
    for (int i = 0; i < 64; ++i) s += gpart[i * EMBED + t];
    gmean[t] = s * (1.0f / N_NODES);
}

// pa[a][h] = proc_emb[a].W1a + team_emb[a].W1b + gmean.W1c + b1   (fp32)
__global__ void k_pa(const float* __restrict__ ne, const int* __restrict__ idx,
                     const float* __restrict__ team, const float* __restrict__ gmean,
                     const float* __restrict__ W1, const float* __restrict__ b1,
                     float* __restrict__ pa) {
    int a = blockIdx.x;
    int h = threadIdx.x;
    __shared__ float vec[768];
    int nid = idx[a];
    vec[h]       = ne[(size_t)nid * EMBED + h];
    vec[256 + h] = team[(a % TEAMS) * EMBED + h];
    vec[512 + h] = gmean[h];
    __syncthreads();
    float acc = b1[h];
#pragma unroll 8
    for (int e = 0; e < 768; ++e) acc = fmaf(vec[e], W1[(size_t)e * HID + h], acc);
    pa[(size_t)a * HID + h] = acc;
}

// pbt[bt][h] = relu(states[bt] @ Ws + bs) @ W1[768:1024]   (fp32)
__global__ void k_pbt(const float* __restrict__ states, const float* __restrict__ Ws,
                      const float* __restrict__ bs, const float* __restrict__ W1,
                      float* __restrict__ pbt) {
    int bt = blockIdx.x;
    int h = threadIdx.x;
    __shared__ float st[STATE];
    __shared__ float se[EMBED];
    if (h < STATE) st[h] = states[(size_t)bt * STATE + h];
    __syncthreads();
    float acc = bs[h];
#pragma unroll 8
    for (int s = 0; s < STATE; ++s) acc = fmaf(st[s], Ws[(size_t)s * EMBED + h], acc);
    se[h] = fmaxf(acc, 0.f);
    __syncthreads();
    float acc2 = 0.f;
#pragma unroll 8
    for (int e = 0; e < EMBED; ++e) acc2 = fmaf(se[e], W1[(size_t)(768 + e) * HID + h], acc2);
    pbt[(size_t)bt * HID + h] = acc2;
}

// split W2 into transposed hi/lo bf16 [n][k]; pack padded pair panel W1pT [n][32]
__global__ void k_split(const float* __restrict__ W1, const float* __restrict__ W2,
                        bf16_t* __restrict__ w2t_hi, bf16_t* __restrict__ w2t_lo,
                        bf16_t* __restrict__ w1pt) {
    int k = blockIdx.x;
    int n = threadIdx.x;
    float x = W2[(size_t)k * HID + n];
    bf16_t hb = (bf16_t)x;
    bf16_t lb = (bf16_t)(x - (float)hb);
    w2t_hi[(size_t)n * HID + k] = hb;
    w2t_lo[(size_t)n * HID + k] = lb;
    if (k < 32) {
        float w = (k < PAIR_F) ? W1[(size_t)(1024 + k) * HID + n] : 0.f;
        w1pt[(size_t)n * 32 + k] = (bf16_t)w;
    }
}

// ---------------- fused main kernel ----------------
// tile: 64 rows x 256 cols, 4 waves (each 64x64), h1 built in LDS (hi/lo split),
// 3-pass bf16 MFMA for h1@W2, fused relu+b2 and W3 dot epilogue.
__global__ __launch_bounds__(256, 2) void k_main(
    const float* __restrict__ pf, const float* __restrict__ pa,
    const float* __restrict__ pbt, const bf16_t* __restrict__ w2t_hi,
    const bf16_t* __restrict__ w2t_lo, const bf16_t* __restrict__ w1pt,
    const float* __restrict__ b2, const float* __restrict__ W3,
    const float* __restrict__ b3, float* __restrict__ out) {
    __shared__ __align__(16) bf16_t Ahi[64 * 256];
    __shared__ __align__(16) bf16_t Alo[64 * 256];
    __shared__ __align__(16) float pfs[64 * PAIR_F];
    __shared__ float red[4 * 64];

    const int tid = threadIdx.x;
    const int wid = tid >> 6;
    const int lane = tid & 63;
    const int c = lane & 15; // frag col (C/D, B) / frag row (A)
    const int q = lane >> 4; // k-group (A,B) / row-group (C/D)

    const int r0 = blockIdx.x * 64;
    const int bt = r0 >> 8;
    const int a0 = r0 & 255;

    // stage 64x14 pair features (contiguous 896 floats)
    if (tid < 224) {
        const float4 v = ((const float4*)(pf + (size_t)r0 * PAIR_F))[tid];
        *(float4*)&pfs[tid * 4] = v;
    }

    const int nbase = wid * 64 + c;
    float pbtv[4], b2v[4], w3v[4];
#pragma unroll
    for (int ni = 0; ni < 4; ++ni) {
        int n = nbase + ni * 16;
        pbtv[ni] = pbt[(size_t)bt * HID + n];
        b2v[ni] = b2[n];
        w3v[ni] = W3[n];
    }

    __syncthreads();

    f32x4 acc[4][4];
#pragma unroll
    for (int mi = 0; mi < 4; ++mi)
#pragma unroll
        for (int ni = 0; ni < 4; ++ni) acc[mi][ni] = f32x4{0.f, 0.f, 0.f, 0.f};

    // ---- pair-part: h1 += pair[64x14] @ W1p[14x256]  (K padded to 32, 1-pass bf16)
    bf16x8 bfragp[4];
#pragma unroll
    for (int ni = 0; ni < 4; ++ni) {
        int n = nbase + ni * 16;
        bfragp[ni] = *(const bf16x8*)(w1pt + (size_t)n * 32 + q * 8);
    }
#pragma unroll
    for (int mi = 0; mi < 4; ++mi) {
        int m = mi * 16 + c;
        bf16x8 afrag;
#pragma unroll
        for (int j = 0; j < 8; ++j) {
            int k = q * 8 + j;
            float v = (k < PAIR_F) ? pfs[m * PAIR_F + k] : 0.f;
            afrag[j] = (bf16_t)v;
        }
#pragma unroll
        for (int ni = 0; ni < 4; ++ni)
            acc[mi][ni] = __builtin_amdgcn_mfma_f32_16x16x32_bf16(afrag, bfragp[ni],
                                                                  acc[mi][ni], 0, 0, 0);
    }

    // ---- h1 = relu(pair + pa + pbt); hi/lo split into swizzled LDS
#pragma unroll
    for (int mi = 0; mi < 4; ++mi) {
#pragma unroll
        for (int j = 0; j < 4; ++j) {
            int m = mi * 16 + q * 4 + j;
            const float* parow = pa + (size_t)(a0 + m) * HID;
#pragma unroll
            for (int ni = 0; ni < 4; ++ni) {
                int n = nbase + ni * 16;
                float h = acc[mi][ni][j] + parow[n] + pbtv[ni];
                h = fmaxf(h, 0.f);
                bf16_t hb = (bf16_t)h;
                bf16_t lb = (bf16_t)(h - (float)hb);
                int idxw = m * 256 + (n ^ ((m & 7) << 3));
                Ahi[idxw] = hb;
                Alo[idxw] = lb;
            }
        }
    }

#pragma unroll
    for (int mi = 0; mi < 4; ++mi)
#pragma unroll
        for (int ni = 0; ni < 4; ++ni) acc[mi][ni] = f32x4{0.f, 0.f, 0.f, 0.f};

    __syncthreads();

    // ---- main GEMM: h2 = h1[64x256] @ W2[256x256], split-bf16 3-pass
#pragma unroll
    for (int ks = 0; ks < 8; ++ks) {
        const int k0 = ks * 32 + q * 8;
        bf16x8 ah[4], al[4], bh[4], bl[4];
#pragma unroll
        for (int ni = 0; ni < 4; ++ni) {
            int n = nbase + ni * 16;
            size_t off = (size_t)n * HID + k0;
            bh[ni] = *(const bf16x8*)(w2t_hi + off);
            bl[ni] = *(const bf16x8*)(w2t_lo + off);
        }
#pragma unroll
        for (int mi = 0; mi < 4; ++mi) {
            int m = mi * 16 + c;
            int idxr = m * 256 + (k0 ^ ((m & 7) << 3));
            ah[mi] = *(const bf16x8*)&Ahi[idxr];
            al[mi] = *(const bf16x8*)&Alo[idxr];
        }
#pragma unroll
        for (int mi = 0; mi < 4; ++mi)
#pragma unroll
            for (int ni = 0; ni < 4; ++ni) {
                acc[mi][ni] = __builtin_amdgcn_mfma_f32_16x16x32_bf16(ah[mi], bh[ni],
                                                                      acc[mi][ni], 0, 0, 0);
                acc[mi][ni] = __builtin_amdgcn_mfma_f32_16x16x32_bf16(ah[mi], bl[ni],
                                                                      acc[mi][ni], 0, 0, 0);
                acc[mi][ni] = __builtin_amdgcn_mfma_f32_16x16x32_bf16(al[mi], bh[ni],
                                                                      acc[mi][ni], 0, 0, 0);
            }
    }

    // ---- epilogue: h2 = relu(acc + b2); partial[row] = h2 . W3 over this wave's cols
    float p[4][4];
#pragma unroll
    for (int mi = 0; mi < 4; ++mi)
#pragma unroll
        for (int j = 0; j < 4; ++j) {
            float s = 0.f;
#pragma unroll
            for (int ni = 0; ni < 4; ++ni)
                s = fmaf(fmaxf(acc[mi][ni][j] + b2v[ni], 0.f), w3v[ni], s);
            p[mi][j] = s;
        }
#pragma unroll
    for (int off = 1; off < 16; off <<= 1)
#pragma unroll
        for (int mi = 0; mi < 4; ++mi)
#pragma unroll
            for (int j = 0; j < 4; ++j) p[mi][j] += __shfl_xor(p[mi][j], off, 64);

    if (c == 0) {
#pragma unroll
        for (int mi = 0; mi < 4; ++mi)
#pragma unroll
            for (int j = 0; j < 4; ++j)
                red[wid * 64 + mi * 16 + q * 4 + j] = p[mi][j];
    }
    __syncthreads();

    if (tid < 64) {
        float s = red[tid] + red[64 + tid] + red[128 + tid] + red[192 + tid] + b3[0];
        out[(size_t)r0 + tid] = s;
    }
}

// ---------------- launch ----------------

extern "C" void kernel_launch(void* const* d_in, const int* in_sizes, int n_in,
                              void* d_out, int out_size, void* d_ws, size_t ws_size,
                              hipStream_t stream) {
    (void)in_sizes; (void)n_in; (void)out_size; (void)ws_size;
    const float* ne     = (const float*)d_in[0];
    const float* states = (const float*)d_in[1];
    const float* pf     = (const float*)d_in[2];
    const int*   idx    = (const int*)d_in[3];
    const float* team   = (const float*)d_in[4];
    const float* Ws     = (const float*)d_in[5];
    const float* bs     = (const float*)d_in[6];
    const float* W1     = (const float*)d_in[7];
    const float* b1     = (const float*)d_in[8];
    const float* W2     = (const float*)d_in[9];
    const float* b2     = (const float*)d_in[10];
    const float* W3     = (const float*)d_in[11];
    const float* b3     = (const float*)d_in[12];
    float* out = (float*)d_out;

    char* ws = (char*)d_ws;
    float* gpart  = (float*)(ws + 0);        //  65536 B
    float* gmean  = (float*)(ws + 65536);    //   1024 B
    float* pa     = (float*)(ws + 66560);    // 262144 B
    float* pbt    = (float*)(ws + 328704);   // 524288 B
    bf16_t* w2hi  = (bf16_t*)(ws + 852992);  // 131072 B
    bf16_t* w2lo  = (bf16_t*)(ws + 984064);  // 131072 B
    bf16_t* w1pt  = (bf16_t*)(ws + 1115136); //  16384 B

    k_colsum_part<<<64, 256, 0, stream>>>(ne, gpart);
    k_colsum_final<<<1, 256, 0, stream>>>(gpart, gmean);
    k_pa<<<256, 256, 0, stream>>>(ne, idx, team, gmean, W1, b1, pa);
    k_pbt<<<512, 256, 0, stream>>>(states, Ws, bs, W1, pbt);
    k_split<<<256, 256, 0, stream>>>(W1, W2, w2hi, w2lo, w1pt);
    k_main<<<M_TOTAL / 64, 256, 0, stream>>>(pf, pa, pbt, w2hi, w2lo, w1pt, b2, W3, b3, out);
}

// Round 2
// 77.265 us; speedup vs baseline: 1.5706x; 1.5706x over previous
//
#include <hip/hip_runtime.h>
#include <hip/hip_bf16.h>

#define N_NODES 2048
#define EMBED 256
#define STATE 128
#define HID 256
#define N_ACT 256
#define TEAMS 8
#define PAIR_F 14
#define BT_TOTAL 512               // B*T
#define M_TOTAL (BT_TOTAL * N_ACT) // 131072

typedef _Float16 f16_t;
typedef _Float16 f16x8 __attribute__((ext_vector_type(8)));
typedef _Float16 f16x4 __attribute__((ext_vector_type(4)));
typedef float f32x4 __attribute__((ext_vector_type(4)));

// reordered weight layout: for (k, n), KB = K/32:
//   g=n>>4, kb=k>>5, q=(k>>3)&3, c=n&15, j=k&7
//   flat = ((g*KB + kb)*4 + q)*128 + c*8 + j
// -> a wave (lanes c,q) reading frag (g, kb) touches contiguous 2KB. Coalesced.
__device__ __forceinline__ size_t reord_idx(int k, int n, int KB) {
    return (size_t)(((n >> 4) * KB + (k >> 5)) * 4 + ((k >> 3) & 3)) * 128 +
           (size_t)(n & 15) * 8 + (k & 7);
}

// ---------------- precompute: column partial sums ----------------
__global__ void k_colsum_part(const float* __restrict__ ne, float* __restrict__ gpart) {
    int b = blockIdx.x;
    int t = threadIdx.x;
    float s = 0.f;
    const float* base = ne + (size_t)b * 32 * EMBED + t;
#pragma unroll
    for (int i = 0; i < 32; ++i) s += base[(size_t)i * EMBED];
    gpart[b * EMBED + t] = s;
}

// ---------------- precompute: gathers + weight reorders (one launch) ----------------
// seg0 vecs_h  [256][768] f16 : [proc | team | gmean]
// seg1 W1abcT  reorder W1[0:768]    KB=24
// seg2 W1dT    reorder W1[768:1024] KB=8
// seg3 WsT     reorder Ws           KB=4
// seg4 W2s     reorder W2           KB=8
// seg5 w1pt    reorder W1[1024:1038] pad K->32, KB=1
// seg6 states_h f16 copy
__global__ void k_prep(const float* __restrict__ ne, const int* __restrict__ idx,
                       const float* __restrict__ team, const float* __restrict__ gpart,
                       const float* __restrict__ states, const float* __restrict__ Ws,
                       const float* __restrict__ W1, const float* __restrict__ W2,
                       f16_t* __restrict__ vecs, f16_t* __restrict__ W1abcT,
                       f16_t* __restrict__ W1dT, f16_t* __restrict__ WsT,
                       f16_t* __restrict__ W2s, f16_t* __restrict__ w1pt,
                       f16_t* __restrict__ states_h) {
    int i = blockIdx.x * 256 + threadIdx.x;
    if (i < 196608) { // vecs
        int a = i / 768, e = i - a * 768;
        float v;
        if (e < 256) v = ne[(size_t)idx[a] * EMBED + e];
        else if (e < 512) v = team[(a % TEAMS) * EMBED + (e - 256)];
        else {
            int h = e - 512;
            float s = 0.f;
#pragma unroll 8
            for (int p = 0; p < 64; ++p) s += gpart[p * EMBED + h];
            v = s * (1.0f / N_NODES);
        }
        vecs[(size_t)a * 768 + e] = (f16_t)v;
        return;
    }
    i -= 196608;
    if (i < 196608) { // W1abcT
        int k = i >> 8, n = i & 255;
        W1abcT[reord_idx(k, n, 24)] = (f16_t)W1[(size_t)k * HID + n];
        return;
    }
    i -= 196608;
    if (i < 65536) { // W1dT
        int k = i >> 8, n = i & 255;
        W1dT[reord_idx(k, n, 8)] = (f16_t)W1[(size_t)(768 + k) * HID + n];
        return;
    }
    i -= 65536;
    if (i < 32768) { // WsT
        int k = i >> 8, n = i & 255;
        WsT[reord_idx(k, n, 4)] = (f16_t)Ws[(size_t)k * EMBED + n];
        return;
    }
    i -= 32768;
    if (i < 65536) { // W2s
        int k = i >> 8, n = i & 255;
        W2s[reord_idx(k, n, 8)] = (f16_t)W2[(size_t)k * HID + n];
        return;
    }
    i -= 65536;
    if (i < 8192) { // w1pt (pad to K=32)
        int k = i >> 8, n = i & 255;
        float v = (k < PAIR_F) ? W1[(size_t)(1024 + k) * HID + n] : 0.f;
        w1pt[reord_idx(k, n, 1)] = (f16_t)v;
        return;
    }
    i -= 8192;
    if (i < 65536) states_h[i] = (f16_t)states[i];
}

// ---------------- generic 64x64-tile fp16 GEMM (4 waves, wave = 64x16) ----------------
__device__ __forceinline__ void gemm_tile64(const f16_t* __restrict__ A, int K, int KB,
                                            const f16_t* __restrict__ Bre,
                                            const float* __restrict__ bias, bool relu,
                                            f16_t* __restrict__ out, int m0, int n0) {
    const int tid = threadIdx.x;
    const int wid = tid >> 6, lane = tid & 63;
    const int c = lane & 15, q = lane >> 4;
    const int n = n0 + wid * 16 + c;
    const int g = n >> 4;
    f32x4 acc[4] = {f32x4{0,0,0,0}, f32x4{0,0,0,0}, f32x4{0,0,0,0}, f32x4{0,0,0,0}};
    for (int ks = 0; ks < KB; ++ks) {
        f16x8 bf = *(const f16x8*)(Bre + (size_t)((g * KB + ks) * 4 + q) * 128 + c * 8);
#pragma unroll
        for (int mi = 0; mi < 4; ++mi) {
            f16x8 af = *(const f16x8*)(A + (size_t)(m0 + mi * 16 + c) * K + ks * 32 + q * 8);
            acc[mi] = __builtin_amdgcn_mfma_f32_16x16x32_f16(af, bf, acc[mi], 0, 0, 0);
        }
    }
    float bv = bias ? bias[n] : 0.f;
#pragma unroll
    for (int mi = 0; mi < 4; ++mi)
#pragma unroll
        for (int j = 0; j < 4; ++j) {
            float v = acc[mi][j] + bv;
            if (relu) v = fmaxf(v, 0.f);
            out[(size_t)(m0 + mi * 16 + q * 4 + j) * HID + n] = (f16_t)v;
        }
}

// se = relu(states@Ws + bs)  [512x256]   blocks 0..31
// pa = vecs@W1abc + b1       [256x256]   blocks 32..47
__global__ __launch_bounds__(256, 4) void k_sepa(
    const f16_t* __restrict__ states_h, const f16_t* __restrict__ WsT,
    const float* __restrict__ bs, const f16_t* __restrict__ vecs,
    const f16_t* __restrict__ W1abcT, const float* __restrict__ b1,
    f16_t* __restrict__ se, f16_t* __restrict__ pa_h) {
    int bid = blockIdx.x;
    if (bid < 32) gemm_tile64(states_h, 128, 4, WsT, bs, true, se, (bid >> 2) * 64, (bid & 3) * 64);
    else {
        int b = bid - 32;
        gemm_tile64(vecs, 768, 24, W1abcT, b1, false, pa_h, (b >> 2) * 64, (b & 3) * 64);
    }
}

// pbt = se@W1d  [512x256]
__global__ __launch_bounds__(256, 4) void k_pbtk(const f16_t* __restrict__ se,
                                                 const f16_t* __restrict__ W1dT,
                                                 f16_t* __restrict__ pbt_h) {
    int b = blockIdx.x;
    gemm_tile64(se, 256, 8, W1dT, nullptr, false, pbt_h, (b >> 2) * 64, (b & 3) * 64);
}

// ---------------- fused main kernel ----------------
// block: 256 thr / 4 waves; tile 128 rows x 256 cols; wave tile = 128x64.
// phase 1 (transposed pair GEMM + pa + pbt + relu -> fp16 LDS, XOR-swizzled)
// phase 2 (h1 @ W2, fp16 single pass), fused relu+b2+W3 epilogue.
__global__ __launch_bounds__(256, 2) void k_main(
    const float* __restrict__ pf, const f16_t* __restrict__ pa,
    const f16_t* __restrict__ pbt, const f16_t* __restrict__ w2s,
    const f16_t* __restrict__ w1pt, const float* __restrict__ b2,
    const float* __restrict__ W3, const float* __restrict__ b3,
    float* __restrict__ out) {
    __shared__ __align__(16) f16_t Ah[128 * 256];
    __shared__ float red[4][128];

    const int tid = threadIdx.x;
    const int wid = tid >> 6, lane = tid & 63;
    const int c = lane & 15, q = lane >> 4;

    const int r0 = blockIdx.x * 128;
    const int bt = r0 >> 8;
    const int a0 = r0 & 255;

    // epilogue constants (phase-2 layout: n = wid*64 + ni*16 + c)
    float b2v[4], w3v[4];
#pragma unroll
    for (int ni = 0; ni < 4; ++ni) {
        int n = wid * 64 + ni * 16 + c;
        b2v[ni] = b2[n];
        w3v[ni] = W3[n];
    }
    // pbt (phase-1 layout: n = wid*64 + nf*16 + q*4 + j)
    float pbtv[4][4];
#pragma unroll
    for (int nf = 0; nf < 4; ++nf) {
        f16x4 t = *(const f16x4*)(pbt + (size_t)bt * HID + wid * 64 + nf * 16 + q * 4);
#pragma unroll
        for (int j = 0; j < 4; ++j) pbtv[nf][j] = (float)t[j];
    }

    f32x4 acc[32];
#pragma unroll
    for (int i = 0; i < 32; ++i) acc[i] = f32x4{0, 0, 0, 0};

    // ---- phase 1: transposed pair GEMM: D[n][m] = w1pt (A) x pf^T (B)
    f16x8 af[4];
#pragma unroll
    for (int nf = 0; nf < 4; ++nf) {
        int g = wid * 4 + nf;
        af[nf] = *(const f16x8*)(w1pt + (size_t)(g * 4 + q) * 128 + c * 8);
    }
#pragma unroll
    for (int mf = 0; mf < 8; ++mf) {
        int m = mf * 16 + c;
        const float* row = pf + (size_t)(r0 + m) * PAIR_F;
        float2 v01{0, 0}, v23{0, 0}, v45{0, 0}, v67{0, 0};
        if (q == 0) {
            v01 = *(const float2*)(row);
            v23 = *(const float2*)(row + 2);
            v45 = *(const float2*)(row + 4);
            v67 = *(const float2*)(row + 6);
        } else if (q == 1) {
            v01 = *(const float2*)(row + 8);
            v23 = *(const float2*)(row + 10);
            v45 = *(const float2*)(row + 12); // k=12,13; rest padded 0
        }
        f16x8 bf;
        bf[0] = (f16_t)v01.x; bf[1] = (f16_t)v01.y;
        bf[2] = (f16_t)v23.x; bf[3] = (f16_t)v23.y;
        bf[4] = (f16_t)v45.x; bf[5] = (f16_t)v45.y;
        bf[6] = (f16_t)v67.x; bf[7] = (f16_t)v67.y;
#pragma unroll
        for (int nf = 0; nf < 4; ++nf)
            acc[nf * 8 + mf] = __builtin_amdgcn_mfma_f32_16x16x32_f16(af[nf], bf, acc[nf * 8 + mf], 0, 0, 0);
    }

    // ---- h1 = relu(pair + pa + pbt) -> fp16, swizzled LDS (row m, k' = n ^ ((m&7)<<3))
#pragma unroll
    for (int nf = 0; nf < 4; ++nf) {
        int n0 = wid * 64 + nf * 16 + q * 4;
#pragma unroll
        for (int mf = 0; mf < 8; ++mf) {
            int m = mf * 16 + c;
            f16x4 pav = *(const f16x4*)(pa + (size_t)(a0 + m) * HID + n0);
            f16x4 hv;
#pragma unroll
            for (int j = 0; j < 4; ++j) {
                float h = acc[nf * 8 + mf][j] + (float)pav[j] + pbtv[nf][j];
                hv[j] = (f16_t)fmaxf(h, 0.f);
            }
            *(f16x4*)(&Ah[m * 256 + (n0 ^ ((m & 7) << 3))]) = hv;
        }
    }

#pragma unroll
    for (int i = 0; i < 32; ++i) acc[i] = f32x4{0, 0, 0, 0};

    __syncthreads();

    // ---- phase 2: h2 = h1[128x256] @ W2[256x256], fp16 single pass
#pragma unroll
    for (int ks = 0; ks < 8; ++ks) {
        f16x8 bh[4];
#pragma unroll
        for (int ni = 0; ni < 4; ++ni) {
            int g = wid * 4 + ni;
            bh[ni] = *(const f16x8*)(w2s + (size_t)((g * 8 + ks) * 4 + q) * 128 + c * 8);
        }
#pragma unroll
        for (int mi = 0; mi < 8; ++mi) {
            int m = mi * 16 + c;
            int kx = (ks * 32 + q * 8) ^ ((m & 7) << 3);
            f16x8 ah = *(const f16x8*)(&Ah[m * 256 + kx]);
#pragma unroll
            for (int ni = 0; ni < 4; ++ni)
                acc[mi * 4 + ni] = __builtin_amdgcn_mfma_f32_16x16x32_f16(ah, bh[ni], acc[mi * 4 + ni], 0, 0, 0);
        }
    }

    // ---- epilogue: score[m] = sum_n relu(h2 + b2) * W3  (+ b3)
    float p[8][4];
#pragma unroll
    for (int mi = 0; mi < 8; ++mi)
#pragma unroll
        for (int j = 0; j < 4; ++j) {
            float s = 0.f;
#pragma unroll
            for (int ni = 0; ni < 4; ++ni)
                s = fmaf(fmaxf(acc[mi * 4 + ni][j] + b2v[ni], 0.f), w3v[ni], s);
            p[mi][j] = s;
        }
#pragma unroll
    for (int off = 1; off < 16; off <<= 1)
#pragma unroll
        for (int mi = 0; mi < 8; ++mi)
#pragma unroll
            for (int j = 0; j < 4; ++j) p[mi][j] += __shfl_xor(p[mi][j], off, 64);

    if (c == 0) {
#pragma unroll
        for (int mi = 0; mi < 8; ++mi)
#pragma unroll
            for (int j = 0; j < 4; ++j) red[wid][mi * 16 + q * 4 + j] = p[mi][j];
    }
    __syncthreads();

    if (tid < 128) {
        out[(size_t)r0 + tid] = red[0][tid] + red[1][tid] + red[2][tid] + red[3][tid] + b3[0];
    }
}

// ---------------- launch ----------------
extern "C" void kernel_launch(void* const* d_in, const int* in_sizes, int n_in,
                              void* d_out, int out_size, void* d_ws, size_t ws_size,
                              hipStream_t stream) {
    (void)in_sizes; (void)n_in; (void)out_size; (void)ws_size;
    const float* ne     = (const float*)d_in[0];
    const float* states = (const float*)d_in[1];
    const float* pf     = (const float*)d_in[2];
    const int*   idx    = (const int*)d_in[3];
    const float* team   = (const float*)d_in[4];
    const float* Ws     = (const float*)d_in[5];
    const float* bs     = (const float*)d_in[6];
    const float* W1     = (const float*)d_in[7];
    const float* b1     = (const float*)d_in[8];
    const float* W2     = (const float*)d_in[9];
    const float* b2     = (const float*)d_in[10];
    const float* W3     = (const float*)d_in[11];
    const float* b3     = (const float*)d_in[12];
    float* out = (float*)d_out;

    char* ws = (char*)d_ws;
    float* gpart    = (float*)(ws + 0);        // 65536
    f16_t* vecs     = (f16_t*)(ws + 65536);    // 393216
    f16_t* W1abcT   = (f16_t*)(ws + 458752);   // 393216
    f16_t* W1dT     = (f16_t*)(ws + 851968);   // 131072
    f16_t* WsT      = (f16_t*)(ws + 983040);   // 65536
    f16_t* W2s      = (f16_t*)(ws + 1048576);  // 131072
    f16_t* w1pt     = (f16_t*)(ws + 1179648);  // 16384
    f16_t* states_h = (f16_t*)(ws + 1196032);  // 131072
    f16_t* se       = (f16_t*)(ws + 1327104);  // 262144
    f16_t* pa_h     = (f16_t*)(ws + 1589248);  // 131072
    f16_t* pbt_h    = (f16_t*)(ws + 1720320);  // 262144  (end 1982464)

    k_colsum_part<<<64, 256, 0, stream>>>(ne, gpart);
    k_prep<<<2464, 256, 0, stream>>>(ne, idx, team, gpart, states, Ws, W1, W2,
                                     vecs, W1abcT, W1dT, WsT, W2s, w1pt, states_h);
    k_sepa<<<48, 256, 0, stream>>>(states_h, WsT, bs, vecs, W1abcT, b1, se, pa_h);
    k_pbtk<<<32, 256, 0, stream>>>(se, W1dT, pbt_h);
    k_main<<<M_TOTAL / 128, 256, 0, stream>>>(pf, pa_h, pbt_h, W2s, w1pt, b2, W3, b3, out);
}